// Round 5
// baseline (606.113 us; speedup 1.0000x reference)
//
#include <hip/hip_runtime.h>
#include <hip/hip_bf16.h>

#define N_    2
#define T_    7
#define C_    96
#define H_    96
#define W_    96
#define HW_   9216
#define HEAD_ 4
#define HD_   24
#define C3_   288
#define PB_   8                      // pixels per block
#define NBLK3_ (N_ * (HW_ / PB_))    // 2304
#define CATP_ 292                    // padded cat row (floats)

typedef unsigned int u32;
typedef unsigned short u16;

__device__ __forceinline__ float bits2f(u32 b) {
    union { u32 u; float f; } x; x.u = b; return x.f;
}
__device__ __forceinline__ float b2f(u16 v) { return bits2f(((u32)v) << 16); }

// scalar element load -> float
template<bool BF16>
__device__ __forceinline__ float ldel(const void* p, size_t i) {
    if constexpr (BF16) return b2f(((const u16*)p)[i]);
    else                return ((const float*)p)[i];
}
// 8 consecutive elements -> float[8] (i % 8 == 0 for alignment)
template<bool BF16>
__device__ __forceinline__ void ld8(const void* p, size_t i, float f[8]) {
    if constexpr (BF16) {
        const uint4 u = *((const uint4*)((const u16*)p + i));
        f[0] = bits2f(u.x << 16); f[1] = bits2f(u.x & 0xFFFF0000u);
        f[2] = bits2f(u.y << 16); f[3] = bits2f(u.y & 0xFFFF0000u);
        f[4] = bits2f(u.z << 16); f[5] = bits2f(u.z & 0xFFFF0000u);
        f[6] = bits2f(u.w << 16); f[7] = bits2f(u.w & 0xFFFF0000u);
    } else {
        const float4 a = *((const float4*)((const float*)p + i));
        const float4 b = *((const float4*)((const float*)p + i + 4));
        f[0] = a.x; f[1] = a.y; f[2] = a.z; f[3] = a.w;
        f[4] = b.x; f[5] = b.y; f[6] = b.z; f[7] = b.w;
    }
}
template<bool BF16>
__device__ __forceinline__ void stel(void* p, size_t i, float v) {
    if constexpr (BF16) ((__hip_bfloat16*)p)[i] = __float2bfloat16(v);
    else                ((float*)p)[i] = v;
}

// ---- dtype detector: writes 1 if bf16, 0 if f32 ----
// (Verified on HW: f32 inputs -> 0; WRITE_SIZE confirms f32 output path.)
__global__ void detect_dtype_kernel(const u32* __restrict__ w, int* __restrict__ flag) {
    u32 x = w[threadIdx.x];
    u32 f = x & 0x7FFFu;
    int inwin = (f >= 0x3A00u) && (f <= 0x4200u);
    unsigned long long m = __ballot(inwin);
    if (threadIdx.x == 0) flag[0] = (__popcll(m) >= 40) ? 1 : 0;
}

// ============ v4: high-MLP fused kernel, dtype-templated ============
// grid = 2304 x 256; 8 pixels/block.
// Correlation: thread = (pixel, frame, head); 24 independent scalar gathers,
// fully unrolled -> many outstanding misses (fetch-latency hiding).
template<bool BF16>
__global__ __launch_bounds__(256) void traj_v4(
    const void* __restrict__ curr, const void* __restrict__ idxf,
    const void* __restrict__ anchor, const void* __restrict__ s1,
    const void* __restrict__ s2, const void* __restrict__ s3,
    const void* __restrict__ loc, const void* __restrict__ pw,
    const void* __restrict__ pbias, const void* __restrict__ fw,
    const void* __restrict__ fbias, void* __restrict__ outp,
    const int* __restrict__ flag)
{
    if ((*flag != 0) != BF16) return;   // uniform early-out for wrong dtype

    __shared__ int   s_lin[T_][PB_];
    __shared__ float s_soft[PB_][HEAD_];
    __shared__ int   s_bidx[PB_][HEAD_];
    __shared__ __align__(16) float s_cat[PB_][CATP_];   // 9344 B
    __shared__ __align__(16) float s_mid[PB_][100];     // 3200 B

    const int tid = threadIdx.x;
    const int b   = blockIdx.x;
    const int nn  = b / (HW_ / PB_);
    const int p0  = (b - nn * (HW_ / PB_)) * PB_;

    // ---- nearest-sample indices (exact reference f32 op sequence) ----
    if (tid < T_ * PB_) {
        int t = tid >> 3, pp = tid & 7;
        int p = p0 + pp;
        float x = ldel<BF16>(loc, (size_t)(nn * 2 * T_ + 2 * t    ) * HW_ + p);
        float y = ldel<BF16>(loc, (size_t)(nn * 2 * T_ + 2 * t + 1) * HW_ + p);
        float gx = 2.0f * x / 95.0f - 1.0f;
        float gy = 2.0f * y / 95.0f - 1.0f;
        float fx = (gx + 1.0f) * 0.5f * 95.0f;
        float fy = (gy + 1.0f) * 0.5f * 95.0f;
        float ix = rintf(fx), iy = rintf(fy);     // round-half-even == jnp.round
        bool v = (ix >= 0.0f) && (ix <= 95.0f) && (iy >= 0.0f) && (iy <= 95.0f);
        s_lin[t][pp] = v ? ((int)iy * W_ + (int)ix) : -1;
    }
    __syncthreads();

    // ---- correlation: lane = (pg, tt, hh) ----
    const int pg = tid >> 5;          // pixel in block, 0..7
    const int l  = tid & 31;
    const int tt = l >> 2;            // frame 0..7 (7 = idle)
    const int hh = l & 3;             // head
    const int p  = p0 + pg;

    // q fragment (same address across tt replicas -> VMEM broadcast)
    float q[HD_];
    float ssqq = 0.f;
    {
        const size_t qoff = (size_t)(nn * C_ + hh * HD_) * HW_ + p;
        #pragma unroll
        for (int j = 0; j < HD_; ++j) {
            float v = ldel<BF16>(curr, qoff + (size_t)j * HW_);
            q[j] = v; ssqq += v * v;
        }
    }
    ssqq += __shfl_xor(ssqq, 1);      // full-c norm: sum over 4 heads (quad)
    ssqq += __shfl_xor(ssqq, 2);
    const float qinv = 1.0f / fmaxf(sqrtf(ssqq), 1e-12f);

    float score = -3.0e38f;
    int   myt   = tt;
    {
        float dot = 0.f, ssk = 0.f;
        if (tt < T_) {
            int lin = s_lin[tt][pg];
            if (lin >= 0) {
                const size_t koff = (size_t)((nn * T_ + tt) * C_ + hh * HD_) * HW_ + lin;
                #pragma unroll
                for (int j = 0; j < HD_; ++j) {
                    float v = ldel<BF16>(idxf, koff + (size_t)j * HW_);
                    dot += v * q[j]; ssk += v * v;
                }
            }
        }
        ssk += __shfl_xor(ssk, 1);    // full-c k norm over the 4 heads (same tt)
        ssk += __shfl_xor(ssk, 2);
        if (tt < T_) {
            float kinv = 1.0f / fmaxf(sqrtf(ssk), 1e-12f);
            score = dot * qinv * kinv;
        }
    }
    // max/argmax over tt (xor 4,8,16 preserves pg,hh); tie -> smaller t (first-max)
    #pragma unroll
    for (int m = 4; m <= 16; m <<= 1) {
        float os = __shfl_xor(score, m);
        int   ot = __shfl_xor(myt, m);
        if (os > score || (os == score && ot < myt)) { score = os; myt = ot; }
    }
    if (tt == 0) { s_soft[pg][hh] = score; s_bidx[pg][hh] = myt; }
    __syncthreads();

    // ---- pick: gather winning frames into cat tile (8 px * 288 scalars) ----
    for (int i = tid; i < PB_ * C3_; i += 256) {       // 9 exact iterations
        int pp = i / C3_, d = i - pp * C3_;
        int set = d / C_, ch = d - set * C_;
        int h = ch / HD_;
        int bt = s_bidx[pp][h];
        int lin = s_lin[bt][pp];
        float v = 0.f;
        if (lin >= 0) {
            const void* sp = (set == 0) ? s1 : (set == 1) ? s2 : s3;
            v = ldel<BF16>(sp, (size_t)((nn * T_ + bt) * C_ + ch) * HW_ + lin);
        }
        s_cat[pp][d] = v;
    }
    __syncthreads();

    // ---- fusion GEMV (96 x 288) + bias, scaled by per-head max score ----
    #pragma unroll
    for (int r = 0; r < 3; ++r) {
        int co = r * 32 + (tid >> 3);
        int pp = tid & 7;
        float acc = 0.f;
        const size_t wbase = (size_t)co * C3_;
        for (int d = 0; d < C3_; d += 8) {
            float wv[8];
            ld8<BF16>(fw, wbase + d, wv);
            const float4 c0 = *((const float4*)&s_cat[pp][d]);
            const float4 c1 = *((const float4*)&s_cat[pp][d + 4]);
            acc += wv[0] * c0.x + wv[1] * c0.y + wv[2] * c0.z + wv[3] * c0.w
                 + wv[4] * c1.x + wv[5] * c1.y + wv[6] * c1.z + wv[7] * c1.w;
        }
        float soft = s_soft[pp][co / HD_];
        s_mid[pp][co] = (acc + ldel<BF16>(fbias, co)) * soft;
    }
    __syncthreads();

    // ---- proj GEMV (96 x 96) + bias + anchor, store ----
    #pragma unroll
    for (int r = 0; r < 3; ++r) {
        int co = r * 32 + (tid >> 3);
        int pp = tid & 7;
        float acc = 0.f;
        const size_t wbase = (size_t)co * C_;
        for (int c = 0; c < C_; c += 8) {
            float wv[8];
            ld8<BF16>(pw, wbase + c, wv);
            const float4 m0 = *((const float4*)&s_mid[pp][c]);
            const float4 m1 = *((const float4*)&s_mid[pp][c + 4]);
            acc += wv[0] * m0.x + wv[1] * m0.y + wv[2] * m0.z + wv[3] * m0.w
                 + wv[4] * m1.x + wv[5] * m1.y + wv[6] * m1.z + wv[7] * m1.w;
        }
        int pq = p0 + pp;
        size_t oidx = (size_t)(nn * C_ + co) * HW_ + pq;
        float res = acc + ldel<BF16>(pbias, co) + ldel<BF16>(anchor, oidx);
        stel<BF16>(outp, oidx, res);
    }
}

extern "C" void kernel_launch(void* const* d_in, const int* in_sizes, int n_in,
                              void* d_out, int out_size, void* d_ws, size_t ws_size,
                              hipStream_t stream) {
    (void)in_sizes; (void)n_in; (void)out_size; (void)ws_size;
    int* flag = (int*)d_ws;
    detect_dtype_kernel<<<1, 64, 0, stream>>>((const u32*)d_in[0], flag);

    dim3 grid(NBLK3_), block(256);
    // f32 instantiation (expected active path on this dataset)
    traj_v4<false><<<grid, block, 0, stream>>>(d_in[0], d_in[1], d_in[2], d_in[3],
                                               d_in[4], d_in[5], d_in[6], d_in[7],
                                               d_in[8], d_in[9], d_in[10], d_out, flag);
    // bf16 instantiation (safety; returns immediately on f32 data)
    traj_v4<true><<<grid, block, 0, stream>>>(d_in[0], d_in[1], d_in[2], d_in[3],
                                              d_in[4], d_in[5], d_in[6], d_in[7],
                                              d_in[8], d_in[9], d_in[10], d_out, flag);
}